// Round 6
// baseline (224.084 us; speedup 1.0000x reference)
//
#include <hip/hip_runtime.h>

#define D_IN  128
#define D_MID 256
#define D_OUT 16
#define NB    512
#define NN    8192
#define NROWS (NB + NN)   // 8704
#define RPB   16          // rows per MLP block -> 544 blocks
#define BT    8           // query rows per KDE block
#define NSLICE 16         // n-slices for KDE
#define SLICE_N (NN / NSLICE)   // 512

// ws layout (floats): Ews[8704*16] | partial[2*16*512*16] | W1T[32768] | W2T[1024]
#define EW_OFF    0
#define PART_OFF  (NROWS * D_OUT)                         // 139264
#define W1T_OFF   (PART_OFF + 2 * NSLICE * NB * D_OUT)    // +262144 = 401408
#define W2T_OFF   (W1T_OFF + D_MID * D_IN)                // 434176

// ---------------- Kernel 0: transpose W1, W2 to coalesced layouts ----------------
__global__ __launch_bounds__(256) void transpose_kernel(
    const float* __restrict__ W1, const float* __restrict__ W2,
    float* __restrict__ W1T, float* __restrict__ W2T)
{
    const int tid = blockIdx.x * 256 + threadIdx.x;
    if (tid < 8192) {
        const int k4 = tid >> 8;            // 0..31
        const int j  = tid & 255;           // 0..255
        const float4 v = reinterpret_cast<const float4*>(W1)[(size_t)j * 32 + k4];
        reinterpret_cast<float4*>(W1T)[(size_t)k4 * 256 + j] = v;
    } else {
        const int t2 = tid - 8192;          // 0..1023
        const int j4 = t2 >> 4;             // 0..63
        const int d  = t2 & 15;             // 0..15
        const float4 v = reinterpret_cast<const float4*>(W2)[(size_t)d * 64 + j4];
        reinterpret_cast<float4*>(W2T)[(size_t)j4 * 16 + d] = v;
    }
}

// ---------------- Kernel 1: Ews[row] = s*(relu(row@W1^T)@W2^T) ----------------
// 256 threads, 16 rows/block, 544 blocks. Thread t holds W1 column t entirely
// in registers (32 float4); rows stream as wave-uniform L1 broadcast loads.
// Steady-state phase 1 touches no LDS and no L2.
__global__ __launch_bounds__(256, 2) void mlp_kernel(
    const float* __restrict__ x, const float* __restrict__ calc_X,
    const float* __restrict__ W1T, const float* __restrict__ W2T,
    const float* __restrict__ hptr, float* __restrict__ Ews)
{
    __shared__ float hid[RPB][272];   // stride 272 floats -> 2-way bank alias (free)

    const int t = threadIdx.x;
    const int row0 = blockIdx.x * RPB;

    // ---- prologue: W1 column t -> 32 float4 registers (coalesced 1KB/wave loads) ----
    float4 w1r[32];
    {
        const float4* __restrict__ w1t4 = reinterpret_cast<const float4*>(W1T);
#pragma unroll
        for (int k4 = 0; k4 < 32; ++k4)
            w1r[k4] = w1t4[k4 * 256 + t];
    }

    // NB = 512 = 32 blocks * 16 rows -> every block is purely x or purely calc_X
    const float* __restrict__ rbase = (row0 < NB)
        ? (x + (size_t)row0 * D_IN)
        : (calc_X + (size_t)(row0 - NB) * D_IN);

    // ---- phase 1: hid[r][t] = relu(row_r . W1col_t), 8 independent FMA chains ----
#pragma unroll 2
    for (int r = 0; r < RPB; ++r) {
        const float4* __restrict__ row4 =
            reinterpret_cast<const float4*>(rbase + (size_t)r * D_IN);
        float4 aA = make_float4(0.f, 0.f, 0.f, 0.f);
        float4 aB = make_float4(0.f, 0.f, 0.f, 0.f);
#pragma unroll
        for (int k4 = 0; k4 < 32; k4 += 2) {
            const float4 v0 = row4[k4];        // wave-uniform broadcast, L1
            const float4 v1 = row4[k4 + 1];
            aA.x = fmaf(w1r[k4].x, v0.x, aA.x);
            aA.y = fmaf(w1r[k4].y, v0.y, aA.y);
            aA.z = fmaf(w1r[k4].z, v0.z, aA.z);
            aA.w = fmaf(w1r[k4].w, v0.w, aA.w);
            aB.x = fmaf(w1r[k4 + 1].x, v1.x, aB.x);
            aB.y = fmaf(w1r[k4 + 1].y, v1.y, aB.y);
            aB.z = fmaf(w1r[k4 + 1].z, v1.z, aB.z);
            aB.w = fmaf(w1r[k4 + 1].w, v1.w, aB.w);
        }
        const float v = (aA.x + aA.y) + (aA.z + aA.w) + ((aB.x + aB.y) + (aB.z + aB.w));
        hid[r][t] = fmaxf(v, 0.f);            // stride-1 across lanes: conflict-free
    }
    __syncthreads();

    // ---- phase 2: one output per thread, Ews[row0+r][d] = s * (hid[r] . W2[d]) ----
    {
        const int r = t >> 4;       // 0..15
        const int d = t & 15;
        const float4* __restrict__ w2t4 = reinterpret_cast<const float4*>(W2T);
        float4 acc = make_float4(0.f, 0.f, 0.f, 0.f);
#pragma unroll 8
        for (int j4 = 0; j4 < 64; ++j4) {
            const float4 wv = w2t4[j4 * 16 + d];   // 256B/16-lane group, L1-resident
            const float4 hv = *reinterpret_cast<const float4*>(&hid[r][j4 * 4]);
            acc.x = fmaf(hv.x, wv.x, acc.x);
            acc.y = fmaf(hv.y, wv.y, acc.y);
            acc.z = fmaf(hv.z, wv.z, acc.z);
            acc.w = fmaf(hv.w, wv.w, acc.w);
        }
        const float s = 0.84932180028801904272f / hptr[0];   // sqrt(log2(e)/2)/h
        Ews[(size_t)(row0 + r) * D_OUT + d] = ((acc.x + acc.y) + (acc.z + acc.w)) * s;
    }
}

// ---------------- Kernel 2: partial KDE sums, w = exp2(-(xs-zs)^2) ----------------
// grid (NB/BT=64, NSLICE=16), 256 threads.
#define GAUSS(xc, yc, zc, num, den) { \
    const float df_ = (xc) - (zc); \
    const float w_ = __builtin_amdgcn_exp2f(-(df_ * df_)); \
    (den) += w_; (num) = fmaf(w_, (yc), (num)); }

__global__ __launch_bounds__(256, 3) void kde_kernel(
    const float* __restrict__ Ews, const float* __restrict__ Y,
    float* __restrict__ partial)
{
    __shared__ float red[4][4][64];

    const int t     = threadIdx.x;
    const int b0    = blockIdx.x * BT;
    const int slice = blockIdx.y;
    const float* __restrict__ Xws = Ews + (size_t)NB * D_OUT;

    const int dg    = t & 3;     // float4 group within the 16 dims
    const int chunk = t >> 2;    // 0..63

    float4 z[BT], num[BT], den[BT];
#pragma unroll
    for (int bt = 0; bt < BT; ++bt) {
        z[bt] = reinterpret_cast<const float4*>(Ews + (size_t)(b0 + bt) * D_OUT)[dg];
        num[bt] = make_float4(0.f, 0.f, 0.f, 0.f);
        den[bt] = make_float4(0.f, 0.f, 0.f, 0.f);
    }

#pragma unroll 2
    for (int i = 0; i < SLICE_N / 64; ++i) {      // 8 iterations
        const int n = slice * SLICE_N + chunk + 64 * i;
        const float4 xw = reinterpret_cast<const float4*>(Xws)[(size_t)n * 4 + dg];
        const float4 yv = reinterpret_cast<const float4*>(Y)[(size_t)n * 4 + dg];
#pragma unroll
        for (int bt = 0; bt < BT; ++bt) {
            GAUSS(xw.x, yv.x, z[bt].x, num[bt].x, den[bt].x);
            GAUSS(xw.y, yv.y, z[bt].y, num[bt].y, den[bt].y);
            GAUSS(xw.z, yv.z, z[bt].z, num[bt].z, den[bt].z);
            GAUSS(xw.w, yv.w, z[bt].w, num[bt].w, den[bt].w);
        }
    }

    // ---- butterfly over chunk bits within wave (lanes sharing dg) ----
    float vals[64];
#pragma unroll
    for (int bt = 0; bt < BT; ++bt) {
        vals[bt * 4 + 0] = num[bt].x; vals[bt * 4 + 1] = num[bt].y;
        vals[bt * 4 + 2] = num[bt].z; vals[bt * 4 + 3] = num[bt].w;
        vals[32 + bt * 4 + 0] = den[bt].x; vals[32 + bt * 4 + 1] = den[bt].y;
        vals[32 + bt * 4 + 2] = den[bt].z; vals[32 + bt * 4 + 3] = den[bt].w;
    }
#pragma unroll
    for (int m = 4; m <= 32; m <<= 1) {
#pragma unroll
        for (int v = 0; v < 64; ++v)
            vals[v] += __shfl_xor(vals[v], m, 64);
    }

    const int wave = t >> 6;     // 0..3
    const int lane = t & 63;
    if (lane < 4) {
#pragma unroll
        for (int v = 0; v < 64; ++v) red[wave][lane][v] = vals[v];
    }
    __syncthreads();

    if (t < 128) {
        const int b = t >> 4;        // 0..7
        const int d = t & 15;
        float nsum = 0.f, dsum = 0.f;
#pragma unroll
        for (int w = 0; w < 4; ++w) {
            nsum += red[w][d >> 2][b * 4 + (d & 3)];
            dsum += red[w][d >> 2][32 + b * 4 + (d & 3)];
        }
        const size_t idx = (size_t)slice * NB * D_OUT + (size_t)(b0 + b) * D_OUT + d;
        partial[idx] = nsum;
        partial[(size_t)NSLICE * NB * D_OUT + idx] = dsum;
    }
}

// ---------------- Kernel 3: combine slices + divide ----------------
__global__ __launch_bounds__(256) void combine_kernel(
    const float* __restrict__ partial, float* __restrict__ out)
{
    const int i = blockIdx.x * 256 + threadIdx.x;   // 0..8191
    float nsum = 0.f, dsum = 0.f;
#pragma unroll
    for (int s = 0; s < NSLICE; ++s) {
        nsum += partial[(size_t)s * NB * D_OUT + i];
        dsum += partial[(size_t)(NSLICE + s) * NB * D_OUT + i];
    }
    out[i] = nsum / dsum;
}

extern "C" void kernel_launch(void* const* d_in, const int* in_sizes, int n_in,
                              void* d_out, int out_size, void* d_ws, size_t ws_size,
                              hipStream_t stream) {
    const float* x      = (const float*)d_in[0];
    const float* calc_X = (const float*)d_in[1];
    const float* calc_Y = (const float*)d_in[2];
    const float* W1     = (const float*)d_in[3];
    const float* W2     = (const float*)d_in[4];
    const float* h      = (const float*)d_in[5];

    float* ws      = (float*)d_ws;
    float* Ews     = ws + EW_OFF;
    float* partial = ws + PART_OFF;
    float* W1T     = ws + W1T_OFF;
    float* W2T     = ws + W2T_OFF;
    float* out     = (float*)d_out;

    transpose_kernel<<<dim3(36), dim3(256), 0, stream>>>(W1, W2, W1T, W2T);
    mlp_kernel<<<dim3(NROWS / RPB), dim3(256), 0, stream>>>(x, calc_X, W1T, W2T, h, Ews);
    kde_kernel<<<dim3(NB / BT, NSLICE), dim3(256), 0, stream>>>(Ews, calc_Y, partial);
    combine_kernel<<<dim3(NB * D_OUT / 256), dim3(256), 0, stream>>>(partial, out);
}

// Round 7
// 54.710 us; speedup vs baseline: 4.0959x; 4.0959x over previous
//
#include <hip/hip_runtime.h>

#define D_IN  128
#define D_MID 256
#define D_OUT 16
#define NB    512
#define NN    8192
#define NROWS (NB + NN)   // 8704
#define RPB   16          // rows per MLP block -> 544 blocks
#define BT    8           // query rows per KDE block
#define NSLICE 8          // n-slices for KDE
#define SLICE_N (NN / NSLICE)   // 1024

// ws layout (floats): Ews[8704*16] | partial[2*8*512*16] | W1T[32768] | W2T[1024]
#define EW_OFF    0
#define PART_OFF  (NROWS * D_OUT)                        // 139264
#define W1T_OFF   (PART_OFF + 2 * NSLICE * NB * D_OUT)   // 270336
#define W2T_OFF   (W1T_OFF + D_MID * D_IN)               // 303104

// ---------------- Kernel 0: transpose W1, W2 to coalesced layouts ----------------
__global__ __launch_bounds__(256) void transpose_kernel(
    const float* __restrict__ W1, const float* __restrict__ W2,
    float* __restrict__ W1T, float* __restrict__ W2T)
{
    const int tid = blockIdx.x * 256 + threadIdx.x;
    if (tid < 8192) {
        const int k4 = tid >> 8;            // 0..31
        const int j  = tid & 255;           // 0..255
        const float4 v = reinterpret_cast<const float4*>(W1)[(size_t)j * 32 + k4];
        reinterpret_cast<float4*>(W1T)[(size_t)k4 * 256 + j] = v;
    } else {
        const int t2 = tid - 8192;          // 0..1023
        const int j4 = t2 >> 4;             // 0..63
        const int d  = t2 & 15;             // 0..15
        const float4 v = reinterpret_cast<const float4*>(W2)[(size_t)d * 64 + j4];
        reinterpret_cast<float4*>(W2T)[(size_t)j4 * 16 + d] = v;
    }
}

// ---------------- Kernel 1: Ews[row] = s*(relu(row@W1^T)@W2^T) ----------------
// 256 threads, 16 rows/block, 544 blocks. Thread t = W1 column t; each W1T
// element is loaded EXACTLY ONCE per block (coalesced); rows are wave-uniform
// scalar-path loads; 16 independent fma chains per thread. No weight arrays.
__global__ __launch_bounds__(256) void mlp_kernel(
    const float* __restrict__ x, const float* __restrict__ calc_X,
    const float* __restrict__ W1T, const float* __restrict__ W2T,
    const float* __restrict__ hptr, float* __restrict__ Ews)
{
    __shared__ float hid[RPB][260];   // 16.6 KB; stride 260 -> phase-2 reads conflict-free

    const int t = threadIdx.x;
    const int row0 = blockIdx.x * RPB;

    // NB = 512 = 32 blocks * 16 rows -> every block is purely x or purely calc_X
    const float* __restrict__ rbase = (row0 < NB)
        ? (x + (size_t)row0 * D_IN)
        : (calc_X + (size_t)(row0 - NB) * D_IN);
    const float4* __restrict__ row4 = reinterpret_cast<const float4*>(rbase);
    const float4* __restrict__ w1t4 = reinterpret_cast<const float4*>(W1T);

    // ---- phase 1: acc[r] = row_r . W1col_t ----
    float acc[RPB] = {};
#pragma unroll 2
    for (int k4 = 0; k4 < 32; ++k4) {
        const float4 wv = w1t4[k4 * 256 + t];       // coalesced, each line once/block
#pragma unroll
        for (int r = 0; r < RPB; ++r) {
            const float4 rv = row4[r * 32 + k4];    // wave-uniform (scalar path)
            acc[r] = fmaf(rv.x, wv.x, fmaf(rv.y, wv.y,
                     fmaf(rv.z, wv.z, fmaf(rv.w, wv.w, acc[r]))));
        }
    }
#pragma unroll
    for (int r = 0; r < RPB; ++r)
        hid[r][t] = fmaxf(acc[r], 0.f);             // lane-stride-1: conflict-free
    __syncthreads();

    // ---- phase 2: Ews[row0+r][d] = s * (hid[r] . W2[d]) ----
    {
        const int r = t >> 4;       // 0..15  (4 distinct rows/wave -> disjoint banks)
        const int d = t & 15;
        const float4* __restrict__ w2t4 = reinterpret_cast<const float4*>(W2T);
        float4 a = make_float4(0.f, 0.f, 0.f, 0.f);
#pragma unroll 8
        for (int j4 = 0; j4 < 64; ++j4) {
            const float4 wv = w2t4[j4 * 16 + d];    // 256B/wave, L1-hot
            const float4 hv = *reinterpret_cast<const float4*>(&hid[r][j4 * 4]);
            a.x = fmaf(hv.x, wv.x, a.x);
            a.y = fmaf(hv.y, wv.y, a.y);
            a.z = fmaf(hv.z, wv.z, a.z);
            a.w = fmaf(hv.w, wv.w, a.w);
        }
        const float s = 0.84932180028801904272f / hptr[0];   // sqrt(log2(e)/2)/h
        Ews[(size_t)(row0 + r) * D_OUT + d] = ((a.x + a.y) + (a.z + a.w)) * s;
    }
}

// ---------------- Kernel 2: partial KDE sums, w = exp2(-(xs-zs)^2) ----------------
// grid (NB/BT=64, NSLICE=8), 256 threads = 16 d x 16 chunk. Scalar coalesced
// loads; per-thread partials = 16 -> reduction is only 2 shfl levels + 1KB LDS.
__global__ __launch_bounds__(256) void kde_kernel(
    const float* __restrict__ Ews, const float* __restrict__ Y,
    float* __restrict__ partial)
{
    __shared__ float red[4][16][16];   // [wave][d][bt*2 + {num,den}]

    const int t     = threadIdx.x;
    const int d     = t & 15;
    const int chunk = t >> 4;          // 0..15
    const int b0    = blockIdx.x * BT;
    const int slice = blockIdx.y;
    const float* __restrict__ Xws = Ews + (size_t)NB * D_OUT;

    float z[BT], num[BT] = {}, den[BT] = {};
#pragma unroll
    for (int bt = 0; bt < BT; ++bt)
        z[bt] = Ews[(size_t)(b0 + bt) * D_OUT + d];

#pragma unroll 4
    for (int i = 0; i < SLICE_N / 16; ++i) {        // 64 iterations
        const int n = slice * SLICE_N + i * 16 + chunk;
        const float xw = Xws[(size_t)n * D_OUT + d];   // 4B/lane, fully coalesced
        const float yv = Y[(size_t)n * D_OUT + d];
#pragma unroll
        for (int bt = 0; bt < BT; ++bt) {
            const float df = xw - z[bt];
            const float w  = __builtin_amdgcn_exp2f(-(df * df));
            den[bt] += w;
            num[bt] = fmaf(w, yv, num[bt]);
        }
    }

    // ---- reduce over chunk lanes within wave: xor 16, 32 (2 levels) ----
    float vals[16];
#pragma unroll
    for (int bt = 0; bt < BT; ++bt) {
        vals[bt * 2 + 0] = num[bt];
        vals[bt * 2 + 1] = den[bt];
    }
#pragma unroll
    for (int m = 16; m <= 32; m <<= 1) {
#pragma unroll
        for (int v = 0; v < 16; ++v)
            vals[v] += __shfl_xor(vals[v], m, 64);
    }

    const int wave = t >> 6;
    if ((t & 63) < 16) {
#pragma unroll
        for (int v = 0; v < 16; ++v) red[wave][d][v] = vals[v];
    }
    __syncthreads();

    // ---- 256 outputs: t = bt(8) x d(16) x p(2) ----
    {
        const int p  = t & 1;
        const int dd = (t >> 1) & 15;
        const int bt = t >> 5;
        const int v  = bt * 2 + p;
        const float sum = red[0][dd][v] + red[1][dd][v] + red[2][dd][v] + red[3][dd][v];
        partial[(size_t)(p * NSLICE + slice) * NB * D_OUT + (size_t)(b0 + bt) * D_OUT + dd] = sum;
    }
}

// ---------------- Kernel 3: combine slices + divide ----------------
__global__ __launch_bounds__(256) void combine_kernel(
    const float* __restrict__ partial, float* __restrict__ out)
{
    const int i = blockIdx.x * 256 + threadIdx.x;   // 0..8191
    float nsum = 0.f, dsum = 0.f;
#pragma unroll
    for (int s = 0; s < NSLICE; ++s) {
        nsum += partial[(size_t)s * NB * D_OUT + i];
        dsum += partial[(size_t)(NSLICE + s) * NB * D_OUT + i];
    }
    out[i] = nsum / dsum;
}

extern "C" void kernel_launch(void* const* d_in, const int* in_sizes, int n_in,
                              void* d_out, int out_size, void* d_ws, size_t ws_size,
                              hipStream_t stream) {
    const float* x      = (const float*)d_in[0];
    const float* calc_X = (const float*)d_in[1];
    const float* calc_Y = (const float*)d_in[2];
    const float* W1     = (const float*)d_in[3];
    const float* W2     = (const float*)d_in[4];
    const float* h      = (const float*)d_in[5];

    float* ws      = (float*)d_ws;
    float* Ews     = ws + EW_OFF;
    float* partial = ws + PART_OFF;
    float* W1T     = ws + W1T_OFF;
    float* W2T     = ws + W2T_OFF;
    float* out     = (float*)d_out;

    transpose_kernel<<<dim3(36), dim3(256), 0, stream>>>(W1, W2, W1T, W2T);
    mlp_kernel<<<dim3(NROWS / RPB), dim3(256), 0, stream>>>(x, calc_X, W1T, W2T, h, Ews);
    kde_kernel<<<dim3(NB / BT, NSLICE), dim3(256), 0, stream>>>(Ews, calc_Y, partial);
    combine_kernel<<<dim3(NB * D_OUT / 256), dim3(256), 0, stream>>>(partial, out);
}